// Round 9
// baseline (388.344 us; speedup 1.0000x reference)
//
#include <hip/hip_runtime.h>
#include <hip/hip_bf16.h>

#define BATCH 16
#define SEQ   512
#define HID   768
#define NH    12
#define HD    64
#define NS    5
#define LOG2E 1.44269504f

typedef __attribute__((ext_vector_type(8))) short short8;
typedef __attribute__((ext_vector_type(4))) short bs4;
typedef __attribute__((ext_vector_type(4))) float floatx4;

#define MFMA16(a, b, c) __builtin_amdgcn_mfma_f32_16x16x32_bf16((a), (b), (c), 0, 0, 0)

// async global->LDS, 16B per lane, dest = wave-uniform base + lane*16
#define GLOAD16(gp, lp) __builtin_amdgcn_global_load_lds( \
    (const __attribute__((address_space(1))) unsigned*)(gp), \
    (__attribute__((address_space(3))) unsigned*)(lp), 16, 0, 0)

static __device__ __forceinline__ short f2bs(float f) {
    // fp32 -> bf16 RNE (finite inputs)
    unsigned x = __builtin_bit_cast(unsigned, f);
    return (short)((x + 0x7fffu + ((x >> 16) & 1u)) >> 16);
}

// ---------- fused prep: hidden cvt | W cvt | bili transpose | mask pack (TRANSPOSED) ----------
// blocks [0,3072): hidden  [3072,3936): W  [3936,3996): bilit  [3996,5020): maskT
// maskT layout: mT[b][j][i] packed bitfield bytes (i contiguous) -> attn loads a dword = 4 i-rows.
__global__ __launch_bounds__(256) void prep_kernel(
    const float* __restrict__ hidden, const float* __restrict__ wq,
    const float* __restrict__ wk, const float* __restrict__ wv,
    const float* __restrict__ bili, const float* __restrict__ smask,
    short* __restrict__ xb, short* __restrict__ Wb, short* __restrict__ bltb,
    unsigned char* __restrict__ mT)
{
    __shared__ short Tl[64][72];   // 9216 B scratch (shorts for bilit, bytes for maskT)
    const int bid = blockIdx.x, tid = threadIdx.x;

    if (bid < 3072) {                       // hidden: 786432 groups of 8
        int i = bid * 256 + tid;
        float4 a = ((const float4*)hidden)[2 * i];
        float4 b = ((const float4*)hidden)[2 * i + 1];
        short8 o;
        o[0] = f2bs(a.x); o[1] = f2bs(a.y); o[2] = f2bs(a.z); o[3] = f2bs(a.w);
        o[4] = f2bs(b.x); o[5] = f2bs(b.y); o[6] = f2bs(b.z); o[7] = f2bs(b.w);
        ((short8*)xb)[i] = o;
    } else if (bid < 3936) {                // W: 3 mats x 288 blocks
        int seg = bid - 3072;
        int mat = seg / 288, blk = seg % 288;
        const float* src = (mat == 0) ? wq : (mat == 1) ? wk : wv;
        int i = blk * 256 + tid;
        float4 a = ((const float4*)src)[2 * i];
        float4 b = ((const float4*)src)[2 * i + 1];
        short8 o;
        o[0] = f2bs(a.x); o[1] = f2bs(a.y); o[2] = f2bs(a.z); o[3] = f2bs(a.w);
        o[4] = f2bs(b.x); o[5] = f2bs(b.y); o[6] = f2bs(b.z); o[7] = f2bs(b.w);
        ((short8*)(Wb + (size_t)mat * HID * HID))[i] = o;
    } else if (bid < 3996) {                // bilit: [s,h,p,q] -> bf16 [s,h,q,p]
        int sh = bid - 3936;
        const float* src = bili + (size_t)sh * 4096;
        short* dst = bltb + (size_t)sh * 4096;
        for (int t = tid; t < 4096; t += 256) Tl[t >> 6][t & 63] = f2bs(src[t]);
        __syncthreads();
        for (int t = tid; t < 4096; t += 256) dst[t] = Tl[t & 63][t >> 6];
    } else {                                // maskT: 1024 blocks, one 64x64 (i,j) tile each
        int t = bid - 3996;
        int b = t >> 6;
        int tile = t & 63;
        int ib0 = (tile >> 3) * 64, jb0 = (tile & 7) * 64;
        unsigned char* Tb = (unsigned char*)Tl;   // 64 x stride-80 bytes (5120 B < 9216)
        const int ii = tid >> 2, jj0 = (tid & 3) * 16;
        const size_t BLL = (size_t)BATCH * SEQ * SEQ;
        const float* sm = smask + (size_t)b * SEQ * SEQ + (size_t)(ib0 + ii) * SEQ + jb0 + jj0;
        unsigned char bytes[16];
#pragma unroll
        for (int jj = 0; jj < 16; ++jj) bytes[jj] = 0;
#pragma unroll
        for (int s = 0; s < NS; ++s) {
            const float4* f = (const float4*)(sm + (size_t)s * BLL);
#pragma unroll
            for (int g = 0; g < 4; ++g) {
                float4 v = f[g];
                bytes[g * 4 + 0] |= (unsigned char)((v.x != 0.f) ? (1u << s) : 0u);
                bytes[g * 4 + 1] |= (unsigned char)((v.y != 0.f) ? (1u << s) : 0u);
                bytes[g * 4 + 2] |= (unsigned char)((v.z != 0.f) ? (1u << s) : 0u);
                bytes[g * 4 + 3] |= (unsigned char)((v.w != 0.f) ? (1u << s) : 0u);
            }
        }
#pragma unroll
        for (int jj = 0; jj < 16; ++jj) Tb[(jj0 + jj) * 80 + ii] = bytes[jj];
        __syncthreads();
        const int jT = tid >> 2, iseg = (tid & 3) * 16;
        uint4 val = *(const uint4*)&Tb[jT * 80 + iseg];
        *(uint4*)&mT[((size_t)b * SEQ + jb0 + jT) * SEQ + ib0 + iseg] = val;
    }
}

// ---------- QKV projection: 128x128 tile + global_load_lds + LDS-transpose epilogue ----------
// q pre-scaled by 0.125*LOG2E; k raw; v -> transposed [B,H,D,L].
__global__ __launch_bounds__(256) void proj_mfma(
    const short* __restrict__ xb, const short* __restrict__ Wb,
    const float* __restrict__ bq, const float* __restrict__ bk, const float* __restrict__ bv,
    short* __restrict__ qo, short* __restrict__ ko, short* __restrict__ vto)
{
    __shared__ short SMEM[16384];    // 32 KB pool
    short* As = SMEM;                // 128*32 shorts (8 KB)
    short* Bs = SMEM + 4096;         // 128*32 shorts (8 KB)

    const int tid = threadIdx.x, lane = tid & 63, w = tid >> 6;
    const int q4 = lane >> 4, c15 = lane & 15;
    const int m0 = blockIdx.x * 128, n0 = blockIdx.y * 128;
    const int wrow = (w & 1) * 64, wcol = (w >> 1) * 64;

    const int srow = lane >> 2;
    const int scol = (lane & 3) * 8;
    const short* gA = xb + (size_t)(m0 + w * 32 + srow) * HID + scol;
    const short* gB = Wb + (size_t)(n0 + w * 32 + srow) * HID + scol;
    short* lA = As + w * 1024;
    short* lB = Bs + w * 1024;

    floatx4 acc[4][4];
#pragma unroll
    for (int i = 0; i < 4; ++i)
#pragma unroll
        for (int j = 0; j < 4; ++j) acc[i][j] = (floatx4){0.f, 0.f, 0.f, 0.f};

    for (int k0 = 0; k0 < HID; k0 += 32) {
        __syncthreads();
        GLOAD16(gA + k0,            lA);
        GLOAD16(gA + k0 + 16 * HID, lA + 512);
        GLOAD16(gB + k0,            lB);
        GLOAD16(gB + k0 + 16 * HID, lB + 512);
        __syncthreads();

        short8 af[4], bf[4];
#pragma unroll
        for (int ri = 0; ri < 4; ++ri)
            af[ri] = *(const short8*)&As[(wrow + ri * 16 + c15) * 32 + q4 * 8];
#pragma unroll
        for (int ci = 0; ci < 4; ++ci)
            bf[ci] = *(const short8*)&Bs[(wcol + ci * 16 + c15) * 32 + q4 * 8];
#pragma unroll
        for (int ri = 0; ri < 4; ++ri)
#pragma unroll
            for (int ci = 0; ci < 4; ++ci)
                acc[ri][ci] = MFMA16(af[ri], bf[ci], acc[ri][ci]);
    }

    __syncthreads();   // all frag reads done before reusing pool as epilogue scratch

    short* Sw = SMEM + w * 4096;   // per-wave disjoint 8 KB scratch

    const int matq = n0 / HID;
    const float* bias = (matq == 0) ? bq : (matq == 1) ? bk : bv;
    const int nmBase = (n0 - matq * HID) + wcol;
    const int h = nmBase >> 6;
    const int mg0 = m0 + wrow;
    const int bb = mg0 >> 9, l0 = mg0 & 511;

    if (matq < 2) {
        const float qsc = (matq == 0) ? (0.125f * LOG2E) : 1.0f;
#pragma unroll
        for (int ci = 0; ci < 4; ++ci) {
            const int col = ci * 16 + c15;
            const float bv2 = bias[nmBase + col];
#pragma unroll
            for (int ri = 0; ri < 4; ++ri)
#pragma unroll
                for (int r = 0; r < 4; ++r) {
                    const int row = ri * 16 + q4 * 4 + r;
                    const int phys = (row << 6) + ((((col >> 3) ^ (row & 7)) << 3) | (col & 7));
                    Sw[phys] = f2bs((acc[ri][ci][r] + bv2) * qsc);
                }
        }
        short* dst = (matq == 0) ? qo : ko;
#pragma unroll
        for (int it2 = 0; it2 < 8; ++it2) {
            const int row = it2 * 8 + (lane >> 3);
            const int g = lane & 7;
            short8 val = *(const short8*)&Sw[(row << 6) + ((g ^ (row & 7)) << 3)];
            *(short8*)&dst[(((size_t)bb * NH + h) * SEQ + (l0 + row)) * HD + g * 8] = val;
        }
    } else {
#pragma unroll
        for (int ci = 0; ci < 4; ++ci) {
            const int d = ci * 16 + c15;
            const float bv2 = bias[nmBase + d];
#pragma unroll
            for (int ri = 0; ri < 4; ++ri) {
                bs4 v4;
#pragma unroll
                for (int r = 0; r < 4; ++r) v4[r] = f2bs(acc[ri][ci][r] + bv2);
                const int lbase = ri * 16 + q4 * 4;
                const int phys = (d << 6) + ((((lbase >> 3) ^ (d & 7)) << 3) | (lbase & 7));
                *(bs4*)&Sw[phys] = v4;
            }
        }
#pragma unroll
        for (int it2 = 0; it2 < 8; ++it2) {
            const int d = it2 * 8 + (lane >> 3);
            const int g = lane & 7;
            short8 val = *(const short8*)&Sw[(d << 6) + ((g ^ (d & 7)) << 3)];
            *(short8*)&vto[(((size_t)bb * NH + h) * HD + d) * SEQ + l0 + g * 8] = val;
        }
    }
}

// ---------- fused biaffine attention: dbuf global_load_lds K/V + transposed-mask dwords ----------
// block = (64 q-rows of one (b,h)); 256 threads / 4 waves; wave w owns rows w*16..+15.
// K/V: XOR-chunk-swizzled LDS (conflict-free unpadded), double-buffered via global_load_lds
// so next tile's DMA overlaps current compute; ONE barrier per j-tile.
__global__ __launch_bounds__(256, 4) void attn_mfma(
    const short* __restrict__ q, const short* __restrict__ k, const short* __restrict__ vt,
    const unsigned char* __restrict__ mT, const float* __restrict__ amask,
    const short* __restrict__ bilit, const float* __restrict__ abs_bias,
    float* __restrict__ out)
{
    __shared__ short KsB[2][4096];   // 64 rows x 64 shorts, chunk-swizzled
    __shared__ short VsB[2][4096];
    __shared__ short Pw[4][16 * 40]; // per-wave P/Qp transpose scratch (32 cols + pad)
    __shared__ float Am[SEQ];        // amask[b]*LOG2E
    __shared__ float abt[32];        // LOG2E*0.125*sum(bits*ab) - 23 (fixed exp2 shift)

    const int idx = blockIdx.x;
    const int bh = idx % 192, it = idx / 192;
    const int b = bh / NH, h = bh % NH;
    const int i0 = it * 64;
    const int tid = threadIdx.x, lane = tid & 63, w = tid >> 6;
    const int q4 = lane >> 4, c15 = lane & 15, x7 = c15 & 7;

    const short* qg = q + (size_t)bh * SEQ * HD;
    const short* kg = k + (size_t)bh * SEQ * HD;
    const short* vg = vt + (size_t)bh * HD * SEQ;

    // staging geometry: slot s = w*128 + i*64 + lane ; r = s>>3 ; phys chunk = s&7 ; global chunk = (s&7)^(r&7)
    const int s0 = w * 128 + lane;
    const int r0 = s0 >> 3, cg0 = (s0 & 7) ^ (r0 & 7);
    const int s1 = s0 + 64;
    const int r1 = s1 >> 3, cg1 = (s1 & 7) ^ (r1 & 7);

    // prefetch tile 0 (overlaps prologue compute)
    GLOAD16(kg + (size_t)r0 * HD + cg0 * 8, &KsB[0][w * 1024]);
    GLOAD16(kg + (size_t)r1 * HD + cg1 * 8, &KsB[0][w * 1024 + 512]);
    GLOAD16(vg + (size_t)r0 * SEQ + cg0 * 8, &VsB[0][w * 1024]);
    GLOAD16(vg + (size_t)r1 * SEQ + cg1 * 8, &VsB[0][w * 1024 + 512]);

    if (tid < 32) {
        float a = 0.f;
#pragma unroll
        for (int s = 0; s < NS; ++s)
            if (tid & (1u << s)) a += abs_bias[s * NH + h];
        abt[tid] = a * (0.125f * LOG2E) - 23.0f;
    }
    for (int c = tid; c < SEQ; c += 256) Am[c] = amask[b * SEQ + c] * LOG2E;

    // Q A-fragments straight from global
    short8 aQ0 = *(const short8*)&qg[(size_t)(i0 + w * 16 + c15) * HD + q4 * 8];
    short8 aQ1 = *(const short8*)&qg[(size_t)(i0 + w * 16 + c15) * HD + 32 + q4 * 8];

    // Qp prologue: 2 passes of 32 cols through the 40-stride Pw (wave-private, no barrier)
    short* pw = &Pw[w][0];
    short8 aP[NS][2];
#pragma unroll
    for (int s = 0; s < NS; ++s) {
        const short* bt = bilit + ((size_t)s * NH + h) * 4096;
#pragma unroll
        for (int half = 0; half < 2; ++half) {
#pragma unroll
            for (int n2 = 0; n2 < 2; ++n2) {
                const int ns = half * 2 + n2;
                short8 bf0 = *(const short8*)&bt[(ns * 16 + c15) * 64 + q4 * 8];
                short8 bf1 = *(const short8*)&bt[(ns * 16 + c15) * 64 + 32 + q4 * 8];
                floatx4 acc = {0.f, 0.f, 0.f, 0.f};
                acc = MFMA16(aQ0, bf0, acc);
                acc = MFMA16(aQ1, bf1, acc);
#pragma unroll
                for (int r = 0; r < 4; ++r)
                    pw[(q4 * 4 + r) * 40 + n2 * 16 + c15] = f2bs(acc[r]);
            }
            aP[s][half] = *(const short8*)&pw[c15 * 40 + q4 * 8];
        }
    }

    float l_part[4] = {0.f, 0.f, 0.f, 0.f};
    floatx4 O[4];
#pragma unroll
    for (int d = 0; d < 4; ++d) O[d] = (floatx4){0.f, 0.f, 0.f, 0.f};

    const int ibase = i0 + w * 16 + q4 * 4;
    const unsigned char* mTb = mT + (size_t)b * SEQ * SEQ;   // [j][i], i contiguous

    // mask dwords for jt=0 (4 i-rows per dword)
    unsigned mv[4];
#pragma unroll
    for (int js = 0; js < 4; ++js)
        mv[js] = *(const unsigned*)&mTb[(size_t)(js * 16 + c15) * SEQ + ibase];

    for (int jt = 0; jt < 8; ++jt) {
        const int j0 = jt * 64;
        __syncthreads();   // tile jt arrived (vmcnt drain) + prior readers of the other buffer done

        // prefetch tile jt+1 (DMA overlaps this tile's compute) + mask dwords jt+1
        unsigned mvn[4];
        if (jt < 7) {
            const int jn = j0 + 64;
            short* kb_ = &KsB[(jt + 1) & 1][w * 1024];
            short* vb_ = &VsB[(jt + 1) & 1][w * 1024];
            GLOAD16(kg + (size_t)(jn + r0) * HD + cg0 * 8, kb_);
            GLOAD16(kg + (size_t)(jn + r1) * HD + cg1 * 8, kb_ + 512);
            GLOAD16(vg + (size_t)r0 * SEQ + jn + cg0 * 8, vb_);
            GLOAD16(vg + (size_t)r1 * SEQ + jn + cg1 * 8, vb_ + 512);
#pragma unroll
            for (int js = 0; js < 4; ++js)
                mvn[js] = *(const unsigned*)&mTb[(size_t)(jn + js * 16 + c15) * SEQ + ibase];
        }

        const short* Kc = KsB[jt & 1];
        const short* Vc = VsB[jt & 1];

#pragma unroll
        for (int js = 0; js < 4; ++js) {
            const int row = js * 16 + c15;
            short8 kf0 = *(const short8*)&Kc[row * 64 + ((q4 ^ x7) << 3)];
            short8 kf1 = *(const short8*)&Kc[row * 64 + (((4 + q4) ^ x7) << 3)];

            floatx4 a0 = {0.f, 0.f, 0.f, 0.f};
            a0 = MFMA16(aQ0, kf0, a0);
            a0 = MFMA16(aQ1, kf1, a0);
            floatx4 as_[NS];
#pragma unroll
            for (int s = 0; s < NS; ++s) {
                floatx4 tacc = {0.f, 0.f, 0.f, 0.f};
                tacc = MFMA16(aP[s][0], kf0, tacc);
                tacc = MFMA16(aP[s][1], kf1, tacc);
                as_[s] = tacc;
            }
            const float amv = Am[j0 + js * 16 + c15];
#pragma unroll
            for (int r = 0; r < 4; ++r) {
                const unsigned mbyte = (mv[js] >> (8 * r)) & 0xffu;
                float sc = a0[r] + amv + abt[mbyte & 31u];
#pragma unroll
                for (int s = 0; s < NS; ++s)
                    sc = fmaf((float)((mbyte >> s) & 1u), as_[s][r], sc);
                float p = __builtin_amdgcn_exp2f(sc);
                l_part[r] += p;
                pw[(q4 * 4 + r) * 40 + (js & 1) * 16 + c15] = f2bs(p);
            }
            if (js & 1) {
                short8 pA = *(const short8*)&pw[c15 * 40 + q4 * 8];
                const int kk = js >> 1;
#pragma unroll
                for (int d = 0; d < 4; ++d) {
                    const int vrow = d * 16 + c15;
                    short8 vb = *(const short8*)&Vc[vrow * 64 + (((kk * 4 + q4) ^ x7) << 3)];
                    O[d] = MFMA16(pA, vb, O[d]);
                }
            }
        }
#pragma unroll
        for (int js = 0; js < 4; ++js) mv[js] = mvn[js];
    }

    // epilogue: reduce l across the 16 j-lanes, normalize, store
#pragma unroll
    for (int r = 0; r < 4; ++r) {
        float l = l_part[r];
        l += __shfl_xor(l, 1);
        l += __shfl_xor(l, 2);
        l += __shfl_xor(l, 4);
        l += __shfl_xor(l, 8);
        float inv = 1.f / l;
        float* orow = out + ((size_t)b * SEQ + ibase + r) * HID + h * HD;
#pragma unroll
        for (int d = 0; d < 4; ++d)
            orow[d * 16 + c15] = O[d][r] * inv;
    }
}

extern "C" void kernel_launch(void* const* d_in, const int* in_sizes, int n_in,
                              void* d_out, int out_size, void* d_ws, size_t ws_size,
                              hipStream_t stream) {
    const float* hidden   = (const float*)d_in[0];
    const float* amask    = (const float*)d_in[1];
    const float* smask    = (const float*)d_in[2];
    const float* Wq       = (const float*)d_in[3];
    const float* bq       = (const float*)d_in[4];
    const float* Wk       = (const float*)d_in[5];
    const float* bk       = (const float*)d_in[6];
    const float* Wv       = (const float*)d_in[7];
    const float* bv       = (const float*)d_in[8];
    const float* bili     = (const float*)d_in[9];
    const float* abs_bias = (const float*)d_in[10];
    float* out = (float*)d_out;

    char* ws = (char*)d_ws;
    const size_t QKV = (size_t)BATCH * NH * SEQ * HD * 2;
    short* qb   = (short*)(ws);
    short* kb   = (short*)(ws + QKV);
    short* vtb  = (short*)(ws + 2 * QKV);
    short* xb   = (short*)(ws + 3 * QKV);
    short* Wb   = (short*)(ws + 4 * QKV);
    short* bltb = (short*)(ws + 4 * QKV + (size_t)3 * HID * HID * 2);
    unsigned char* mT = (unsigned char*)(ws + 4 * QKV + (size_t)3 * HID * HID * 2
                                         + (size_t)NS * NH * HD * HD * 2);

    prep_kernel<<<5020, 256, 0, stream>>>(hidden, Wq, Wk, Wv, bili, smask,
                                          xb, Wb, bltb, mT);

    proj_mfma<<<dim3(BATCH * SEQ / 128, 3 * HID / 128), 256, 0, stream>>>(
        xb, Wb, bq, bk, bv, qb, kb, vtb);

    attn_mfma<<<(SEQ / 64) * NH * BATCH, 256, 0, stream>>>(
        qb, kb, vtb, mT, amask, bltb, abs_bias, out);
}

// Round 10
// 321.901 us; speedup vs baseline: 1.2064x; 1.2064x over previous
//
#include <hip/hip_runtime.h>
#include <hip/hip_bf16.h>

#define BATCH 16
#define SEQ   512
#define HID   768
#define NH    12
#define HD    64
#define NS    5
#define LOG2E 1.44269504f

typedef __attribute__((ext_vector_type(8))) short short8;
typedef __attribute__((ext_vector_type(4))) short bs4;
typedef __attribute__((ext_vector_type(4))) float floatx4;

#define MFMA16(a, b, c) __builtin_amdgcn_mfma_f32_16x16x32_bf16((a), (b), (c), 0, 0, 0)

// async global->LDS, 16B per lane, dest = wave-uniform base + lane*16
#define GLOAD16(gp, lp) __builtin_amdgcn_global_load_lds( \
    (const __attribute__((address_space(1))) unsigned*)(gp), \
    (__attribute__((address_space(3))) unsigned*)(lp), 16, 0, 0)

static __device__ __forceinline__ short f2bs(float f) {
    // fp32 -> bf16 RNE (finite inputs)
    unsigned x = __builtin_bit_cast(unsigned, f);
    return (short)((x + 0x7fffu + ((x >> 16) & 1u)) >> 16);
}

// ---------- fused prep: hidden cvt | W cvt | bili transpose | mask pack (TRANSPOSED) ----------
// blocks [0,3072): hidden  [3072,3936): W  [3936,3996): bilit  [3996,5020): maskT
// maskT layout: mT[b][j][i] packed bitfield bytes (i contiguous) -> attn loads a dword = 4 i-rows.
__global__ __launch_bounds__(256) void prep_kernel(
    const float* __restrict__ hidden, const float* __restrict__ wq,
    const float* __restrict__ wk, const float* __restrict__ wv,
    const float* __restrict__ bili, const float* __restrict__ smask,
    short* __restrict__ xb, short* __restrict__ Wb, short* __restrict__ bltb,
    unsigned char* __restrict__ mT)
{
    __shared__ short Tl[64][72];   // 9216 B scratch (shorts for bilit, bytes for maskT)
    const int bid = blockIdx.x, tid = threadIdx.x;

    if (bid < 3072) {                       // hidden: 786432 groups of 8
        int i = bid * 256 + tid;
        float4 a = ((const float4*)hidden)[2 * i];
        float4 b = ((const float4*)hidden)[2 * i + 1];
        short8 o;
        o[0] = f2bs(a.x); o[1] = f2bs(a.y); o[2] = f2bs(a.z); o[3] = f2bs(a.w);
        o[4] = f2bs(b.x); o[5] = f2bs(b.y); o[6] = f2bs(b.z); o[7] = f2bs(b.w);
        ((short8*)xb)[i] = o;
    } else if (bid < 3936) {                // W: 3 mats x 288 blocks
        int seg = bid - 3072;
        int mat = seg / 288, blk = seg % 288;
        const float* src = (mat == 0) ? wq : (mat == 1) ? wk : wv;
        int i = blk * 256 + tid;
        float4 a = ((const float4*)src)[2 * i];
        float4 b = ((const float4*)src)[2 * i + 1];
        short8 o;
        o[0] = f2bs(a.x); o[1] = f2bs(a.y); o[2] = f2bs(a.z); o[3] = f2bs(a.w);
        o[4] = f2bs(b.x); o[5] = f2bs(b.y); o[6] = f2bs(b.z); o[7] = f2bs(b.w);
        ((short8*)(Wb + (size_t)mat * HID * HID))[i] = o;
    } else if (bid < 3996) {                // bilit: [s,h,p,q] -> bf16 [s,h,q,p]
        int sh = bid - 3936;
        const float* src = bili + (size_t)sh * 4096;
        short* dst = bltb + (size_t)sh * 4096;
        for (int t = tid; t < 4096; t += 256) Tl[t >> 6][t & 63] = f2bs(src[t]);
        __syncthreads();
        for (int t = tid; t < 4096; t += 256) dst[t] = Tl[t & 63][t >> 6];
    } else {                                // maskT: 1024 blocks, one 64x64 (i,j) tile each
        int t = bid - 3996;
        int b = t >> 6;
        int tile = t & 63;
        int ib0 = (tile >> 3) * 64, jb0 = (tile & 7) * 64;
        unsigned char* Tb = (unsigned char*)Tl;   // 64 x stride-80 bytes (5120 B < 9216)
        const int ii = tid >> 2, jj0 = (tid & 3) * 16;
        const size_t BLL = (size_t)BATCH * SEQ * SEQ;
        const float* sm = smask + (size_t)b * SEQ * SEQ + (size_t)(ib0 + ii) * SEQ + jb0 + jj0;
        unsigned char bytes[16];
#pragma unroll
        for (int jj = 0; jj < 16; ++jj) bytes[jj] = 0;
#pragma unroll
        for (int s = 0; s < NS; ++s) {
            const float4* f = (const float4*)(sm + (size_t)s * BLL);
#pragma unroll
            for (int g = 0; g < 4; ++g) {
                float4 v = f[g];
                bytes[g * 4 + 0] |= (unsigned char)((v.x != 0.f) ? (1u << s) : 0u);
                bytes[g * 4 + 1] |= (unsigned char)((v.y != 0.f) ? (1u << s) : 0u);
                bytes[g * 4 + 2] |= (unsigned char)((v.z != 0.f) ? (1u << s) : 0u);
                bytes[g * 4 + 3] |= (unsigned char)((v.w != 0.f) ? (1u << s) : 0u);
            }
        }
#pragma unroll
        for (int jj = 0; jj < 16; ++jj) Tb[(jj0 + jj) * 80 + ii] = bytes[jj];
        __syncthreads();
        const int jT = tid >> 2, iseg = (tid & 3) * 16;
        uint4 val = *(const uint4*)&Tb[jT * 80 + iseg];
        *(uint4*)&mT[((size_t)b * SEQ + jb0 + jT) * SEQ + ib0 + iseg] = val;
    }
}

// ---------- QKV projection: 128x128 tile + global_load_lds + LDS-transpose epilogue ----------
// q pre-scaled by 0.125*LOG2E; k raw; v -> transposed [B,H,D,L].
__global__ __launch_bounds__(256) void proj_mfma(
    const short* __restrict__ xb, const short* __restrict__ Wb,
    const float* __restrict__ bq, const float* __restrict__ bk, const float* __restrict__ bv,
    short* __restrict__ qo, short* __restrict__ ko, short* __restrict__ vto)
{
    __shared__ short SMEM[16384];    // 32 KB pool
    short* As = SMEM;                // 128*32 shorts (8 KB)
    short* Bs = SMEM + 4096;         // 128*32 shorts (8 KB)

    const int tid = threadIdx.x, lane = tid & 63, w = tid >> 6;
    const int q4 = lane >> 4, c15 = lane & 15;
    const int m0 = blockIdx.x * 128, n0 = blockIdx.y * 128;
    const int wrow = (w & 1) * 64, wcol = (w >> 1) * 64;

    const int srow = lane >> 2;
    const int scol = (lane & 3) * 8;
    const short* gA = xb + (size_t)(m0 + w * 32 + srow) * HID + scol;
    const short* gB = Wb + (size_t)(n0 + w * 32 + srow) * HID + scol;
    short* lA = As + w * 1024;
    short* lB = Bs + w * 1024;

    floatx4 acc[4][4];
#pragma unroll
    for (int i = 0; i < 4; ++i)
#pragma unroll
        for (int j = 0; j < 4; ++j) acc[i][j] = (floatx4){0.f, 0.f, 0.f, 0.f};

    for (int k0 = 0; k0 < HID; k0 += 32) {
        __syncthreads();
        GLOAD16(gA + k0,            lA);
        GLOAD16(gA + k0 + 16 * HID, lA + 512);
        GLOAD16(gB + k0,            lB);
        GLOAD16(gB + k0 + 16 * HID, lB + 512);
        __syncthreads();

        short8 af[4], bf[4];
#pragma unroll
        for (int ri = 0; ri < 4; ++ri)
            af[ri] = *(const short8*)&As[(wrow + ri * 16 + c15) * 32 + q4 * 8];
#pragma unroll
        for (int ci = 0; ci < 4; ++ci)
            bf[ci] = *(const short8*)&Bs[(wcol + ci * 16 + c15) * 32 + q4 * 8];
#pragma unroll
        for (int ri = 0; ri < 4; ++ri)
#pragma unroll
            for (int ci = 0; ci < 4; ++ci)
                acc[ri][ci] = MFMA16(af[ri], bf[ci], acc[ri][ci]);
    }

    __syncthreads();   // all frag reads done before reusing pool as epilogue scratch

    short* Sw = SMEM + w * 4096;   // per-wave disjoint 8 KB scratch

    const int matq = n0 / HID;
    const float* bias = (matq == 0) ? bq : (matq == 1) ? bk : bv;
    const int nmBase = (n0 - matq * HID) + wcol;
    const int h = nmBase >> 6;
    const int mg0 = m0 + wrow;
    const int bb = mg0 >> 9, l0 = mg0 & 511;

    if (matq < 2) {
        const float qsc = (matq == 0) ? (0.125f * LOG2E) : 1.0f;
#pragma unroll
        for (int ci = 0; ci < 4; ++ci) {
            const int col = ci * 16 + c15;
            const float bv2 = bias[nmBase + col];
#pragma unroll
            for (int ri = 0; ri < 4; ++ri)
#pragma unroll
                for (int r = 0; r < 4; ++r) {
                    const int row = ri * 16 + q4 * 4 + r;
                    const int phys = (row << 6) + ((((col >> 3) ^ (row & 7)) << 3) | (col & 7));
                    Sw[phys] = f2bs((acc[ri][ci][r] + bv2) * qsc);
                }
        }
        short* dst = (matq == 0) ? qo : ko;
#pragma unroll
        for (int it2 = 0; it2 < 8; ++it2) {
            const int row = it2 * 8 + (lane >> 3);
            const int g = lane & 7;
            short8 val = *(const short8*)&Sw[(row << 6) + ((g ^ (row & 7)) << 3)];
            *(short8*)&dst[(((size_t)bb * NH + h) * SEQ + (l0 + row)) * HD + g * 8] = val;
        }
    } else {
#pragma unroll
        for (int ci = 0; ci < 4; ++ci) {
            const int d = ci * 16 + c15;
            const float bv2 = bias[nmBase + d];
#pragma unroll
            for (int ri = 0; ri < 4; ++ri) {
                bs4 v4;
#pragma unroll
                for (int r = 0; r < 4; ++r) v4[r] = f2bs(acc[ri][ci][r] + bv2);
                const int lbase = ri * 16 + q4 * 4;
                const int phys = (d << 6) + ((((lbase >> 3) ^ (d & 7)) << 3) | (lbase & 7));
                *(bs4*)&Sw[phys] = v4;
            }
        }
#pragma unroll
        for (int it2 = 0; it2 < 8; ++it2) {
            const int d = it2 * 8 + (lane >> 3);
            const int g = lane & 7;
            short8 val = *(const short8*)&Sw[(d << 6) + ((g ^ (d & 7)) << 3)];
            *(short8*)&vto[(((size_t)bb * NH + h) * HD + d) * SEQ + l0 + g * 8] = val;
        }
    }
}

// ---------- fused biaffine attention: dbuf global_load_lds K/V + transposed-mask dwords ----------
// block = (64 q-rows of one (b,h)); 256 threads / 4 waves; wave w owns rows w*16..+15.
// K/V: XOR-chunk-swizzled LDS (conflict-free unpadded), double-buffered via global_load_lds
// so next tile's DMA overlaps current compute; ONE barrier per j-tile.
// NOTE: no min-waves clause — R9's (256,4) capped VGPRs at 64 and caused ~400 MB of
// scratch spill traffic per dispatch (WRITE_SIZE 24->222 MB). LDS caps us at 3 blocks/CU anyway.
__global__ __launch_bounds__(256) void attn_mfma(
    const short* __restrict__ q, const short* __restrict__ k, const short* __restrict__ vt,
    const unsigned char* __restrict__ mT, const float* __restrict__ amask,
    const short* __restrict__ bilit, const float* __restrict__ abs_bias,
    float* __restrict__ out)
{
    __shared__ short KsB[2][4096];   // 64 rows x 64 shorts, chunk-swizzled
    __shared__ short VsB[2][4096];
    __shared__ short Pw[4][16 * 40]; // per-wave P/Qp transpose scratch (32 cols + pad)
    __shared__ float Am[SEQ];        // amask[b]*LOG2E
    __shared__ float abt[32];        // LOG2E*0.125*sum(bits*ab) - 23 (fixed exp2 shift)

    const int idx = blockIdx.x;
    const int bh = idx % 192, it = idx / 192;
    const int b = bh / NH, h = bh % NH;
    const int i0 = it * 64;
    const int tid = threadIdx.x, lane = tid & 63, w = tid >> 6;
    const int q4 = lane >> 4, c15 = lane & 15, x7 = c15 & 7;

    const short* qg = q + (size_t)bh * SEQ * HD;
    const short* kg = k + (size_t)bh * SEQ * HD;
    const short* vg = vt + (size_t)bh * HD * SEQ;

    // staging geometry: slot s = w*128 + i*64 + lane ; r = s>>3 ; phys chunk = s&7 ; global chunk = (s&7)^(r&7)
    const int s0 = w * 128 + lane;
    const int r0 = s0 >> 3, cg0 = (s0 & 7) ^ (r0 & 7);
    const int s1 = s0 + 64;
    const int r1 = s1 >> 3, cg1 = (s1 & 7) ^ (r1 & 7);

    // prefetch tile 0 (overlaps prologue compute)
    GLOAD16(kg + (size_t)r0 * HD + cg0 * 8, &KsB[0][w * 1024]);
    GLOAD16(kg + (size_t)r1 * HD + cg1 * 8, &KsB[0][w * 1024 + 512]);
    GLOAD16(vg + (size_t)r0 * SEQ + cg0 * 8, &VsB[0][w * 1024]);
    GLOAD16(vg + (size_t)r1 * SEQ + cg1 * 8, &VsB[0][w * 1024 + 512]);

    if (tid < 32) {
        float a = 0.f;
#pragma unroll
        for (int s = 0; s < NS; ++s)
            if (tid & (1u << s)) a += abs_bias[s * NH + h];
        abt[tid] = a * (0.125f * LOG2E) - 23.0f;
    }
    for (int c = tid; c < SEQ; c += 256) Am[c] = amask[b * SEQ + c] * LOG2E;

    // Q A-fragments straight from global
    short8 aQ0 = *(const short8*)&qg[(size_t)(i0 + w * 16 + c15) * HD + q4 * 8];
    short8 aQ1 = *(const short8*)&qg[(size_t)(i0 + w * 16 + c15) * HD + 32 + q4 * 8];

    // Qp prologue: 2 passes of 32 cols through the 40-stride Pw (wave-private, no barrier)
    short* pw = &Pw[w][0];
    short8 aP[NS][2];
#pragma unroll
    for (int s = 0; s < NS; ++s) {
        const short* bt = bilit + ((size_t)s * NH + h) * 4096;
#pragma unroll
        for (int half = 0; half < 2; ++half) {
#pragma unroll
            for (int n2 = 0; n2 < 2; ++n2) {
                const int ns = half * 2 + n2;
                short8 bf0 = *(const short8*)&bt[(ns * 16 + c15) * 64 + q4 * 8];
                short8 bf1 = *(const short8*)&bt[(ns * 16 + c15) * 64 + 32 + q4 * 8];
                floatx4 acc = {0.f, 0.f, 0.f, 0.f};
                acc = MFMA16(aQ0, bf0, acc);
                acc = MFMA16(aQ1, bf1, acc);
#pragma unroll
                for (int r = 0; r < 4; ++r)
                    pw[(q4 * 4 + r) * 40 + n2 * 16 + c15] = f2bs(acc[r]);
            }
            aP[s][half] = *(const short8*)&pw[c15 * 40 + q4 * 8];
        }
    }

    float l_part[4] = {0.f, 0.f, 0.f, 0.f};
    floatx4 O[4];
#pragma unroll
    for (int d = 0; d < 4; ++d) O[d] = (floatx4){0.f, 0.f, 0.f, 0.f};

    const int ibase = i0 + w * 16 + q4 * 4;
    const unsigned char* mTb = mT + (size_t)b * SEQ * SEQ;   // [j][i], i contiguous

    // mask dwords for jt=0 (4 i-rows per dword)
    unsigned mv[4];
#pragma unroll
    for (int js = 0; js < 4; ++js)
        mv[js] = *(const unsigned*)&mTb[(size_t)(js * 16 + c15) * SEQ + ibase];

    for (int jt = 0; jt < 8; ++jt) {
        const int j0 = jt * 64;
        __syncthreads();   // tile jt arrived (vmcnt drain) + prior readers of the other buffer done

        // prefetch tile jt+1 (DMA overlaps this tile's compute) + mask dwords jt+1
        unsigned mvn[4] = {0u, 0u, 0u, 0u};
        if (jt < 7) {
            const int jn = j0 + 64;
            short* kb_ = &KsB[(jt + 1) & 1][w * 1024];
            short* vb_ = &VsB[(jt + 1) & 1][w * 1024];
            GLOAD16(kg + (size_t)(jn + r0) * HD + cg0 * 8, kb_);
            GLOAD16(kg + (size_t)(jn + r1) * HD + cg1 * 8, kb_ + 512);
            GLOAD16(vg + (size_t)r0 * SEQ + jn + cg0 * 8, vb_);
            GLOAD16(vg + (size_t)r1 * SEQ + jn + cg1 * 8, vb_ + 512);
#pragma unroll
            for (int js = 0; js < 4; ++js)
                mvn[js] = *(const unsigned*)&mTb[(size_t)(jn + js * 16 + c15) * SEQ + ibase];
        }

        const short* Kc = KsB[jt & 1];
        const short* Vc = VsB[jt & 1];

#pragma unroll
        for (int js = 0; js < 4; ++js) {
            const int row = js * 16 + c15;
            short8 kf0 = *(const short8*)&Kc[row * 64 + ((q4 ^ x7) << 3)];
            short8 kf1 = *(const short8*)&Kc[row * 64 + (((4 + q4) ^ x7) << 3)];

            floatx4 a0 = {0.f, 0.f, 0.f, 0.f};
            a0 = MFMA16(aQ0, kf0, a0);
            a0 = MFMA16(aQ1, kf1, a0);
            floatx4 as_[NS];
#pragma unroll
            for (int s = 0; s < NS; ++s) {
                floatx4 tacc = {0.f, 0.f, 0.f, 0.f};
                tacc = MFMA16(aP[s][0], kf0, tacc);
                tacc = MFMA16(aP[s][1], kf1, tacc);
                as_[s] = tacc;
            }
            const float amv = Am[j0 + js * 16 + c15];
#pragma unroll
            for (int r = 0; r < 4; ++r) {
                const unsigned mbyte = (mv[js] >> (8 * r)) & 0xffu;
                float sc = a0[r] + amv + abt[mbyte & 31u];
#pragma unroll
                for (int s = 0; s < NS; ++s)
                    sc = fmaf((float)((mbyte >> s) & 1u), as_[s][r], sc);
                float p = __builtin_amdgcn_exp2f(sc);
                l_part[r] += p;
                pw[(q4 * 4 + r) * 40 + (js & 1) * 16 + c15] = f2bs(p);
            }
            if (js & 1) {
                short8 pA = *(const short8*)&pw[c15 * 40 + q4 * 8];
                const int kk = js >> 1;
#pragma unroll
                for (int d = 0; d < 4; ++d) {
                    const int vrow = d * 16 + c15;
                    short8 vb = *(const short8*)&Vc[vrow * 64 + (((kk * 4 + q4) ^ x7) << 3)];
                    O[d] = MFMA16(pA, vb, O[d]);
                }
            }
        }
#pragma unroll
        for (int js = 0; js < 4; ++js) mv[js] = mvn[js];
    }

    // epilogue: reduce l across the 16 j-lanes, normalize, store
#pragma unroll
    for (int r = 0; r < 4; ++r) {
        float l = l_part[r];
        l += __shfl_xor(l, 1);
        l += __shfl_xor(l, 2);
        l += __shfl_xor(l, 4);
        l += __shfl_xor(l, 8);
        float inv = 1.f / l;
        float* orow = out + ((size_t)b * SEQ + ibase + r) * HID + h * HD;
#pragma unroll
        for (int d = 0; d < 4; ++d)
            orow[d * 16 + c15] = O[d][r] * inv;
    }
}

extern "C" void kernel_launch(void* const* d_in, const int* in_sizes, int n_in,
                              void* d_out, int out_size, void* d_ws, size_t ws_size,
                              hipStream_t stream) {
    const float* hidden   = (const float*)d_in[0];
    const float* amask    = (const float*)d_in[1];
    const float* smask    = (const float*)d_in[2];
    const float* Wq       = (const float*)d_in[3];
    const float* bq       = (const float*)d_in[4];
    const float* Wk       = (const float*)d_in[5];
    const float* bk       = (const float*)d_in[6];
    const float* Wv       = (const float*)d_in[7];
    const float* bv       = (const float*)d_in[8];
    const float* bili     = (const float*)d_in[9];
    const float* abs_bias = (const float*)d_in[10];
    float* out = (float*)d_out;

    char* ws = (char*)d_ws;
    const size_t QKV = (size_t)BATCH * NH * SEQ * HD * 2;
    short* qb   = (short*)(ws);
    short* kb   = (short*)(ws + QKV);
    short* vtb  = (short*)(ws + 2 * QKV);
    short* xb   = (short*)(ws + 3 * QKV);
    short* Wb   = (short*)(ws + 4 * QKV);
    short* bltb = (short*)(ws + 4 * QKV + (size_t)3 * HID * HID * 2);
    unsigned char* mT = (unsigned char*)(ws + 4 * QKV + (size_t)3 * HID * HID * 2
                                         + (size_t)NS * NH * HD * HD * 2);

    prep_kernel<<<5020, 256, 0, stream>>>(hidden, Wq, Wk, Wv, bili, smask,
                                          xb, Wb, bltb, mT);

    proj_mfma<<<dim3(BATCH * SEQ / 128, 3 * HID / 128), 256, 0, stream>>>(
        xb, Wb, bq, bk, bv, qb, kb, vtb);

    attn_mfma<<<(SEQ / 64) * NH * BATCH, 256, 0, stream>>>(
        qb, kb, vtb, mT, amask, bltb, abs_bias, out);
}

// Round 11
// 308.901 us; speedup vs baseline: 1.2572x; 1.0421x over previous
//
#include <hip/hip_runtime.h>
#include <hip/hip_bf16.h>

#define BATCH 16
#define SEQ   512
#define HID   768
#define NH    12
#define HD    64
#define NS    5
#define LOG2E 1.44269504f

typedef __attribute__((ext_vector_type(8))) short short8;
typedef __attribute__((ext_vector_type(4))) short bs4;
typedef __attribute__((ext_vector_type(4))) float floatx4;

#define MFMA16(a, b, c) __builtin_amdgcn_mfma_f32_16x16x32_bf16((a), (b), (c), 0, 0, 0)

// async global->LDS, 16B per lane, dest = wave-uniform base + lane*16
#define GLOAD16(gp, lp) __builtin_amdgcn_global_load_lds( \
    (const __attribute__((address_space(1))) unsigned*)(gp), \
    (__attribute__((address_space(3))) unsigned*)(lp), 16, 0, 0)

static __device__ __forceinline__ short f2bs(float f) {
    // fp32 -> bf16 RNE (finite inputs)
    unsigned x = __builtin_bit_cast(unsigned, f);
    return (short)((x + 0x7fffu + ((x >> 16) & 1u)) >> 16);
}

// ---------- fused prep: hidden cvt | W cvt | bili transpose | mask pack (TRANSPOSED) ----------
// blocks [0,3072): hidden  [3072,3936): W  [3936,3996): bilit  [3996,5020): maskT
// maskT layout: mT[b][j][i] packed bitfield bytes (i contiguous) -> attn loads a dword = 4 i-rows.
__global__ __launch_bounds__(256) void prep_kernel(
    const float* __restrict__ hidden, const float* __restrict__ wq,
    const float* __restrict__ wk, const float* __restrict__ wv,
    const float* __restrict__ bili, const float* __restrict__ smask,
    short* __restrict__ xb, short* __restrict__ Wb, short* __restrict__ bltb,
    unsigned char* __restrict__ mT)
{
    __shared__ short Tl[64][72];   // 9216 B scratch (shorts for bilit, dwords for maskT)
    const int bid = blockIdx.x, tid = threadIdx.x;

    if (bid < 3072) {                       // hidden: 786432 groups of 8
        int i = bid * 256 + tid;
        float4 a = ((const float4*)hidden)[2 * i];
        float4 b = ((const float4*)hidden)[2 * i + 1];
        short8 o;
        o[0] = f2bs(a.x); o[1] = f2bs(a.y); o[2] = f2bs(a.z); o[3] = f2bs(a.w);
        o[4] = f2bs(b.x); o[5] = f2bs(b.y); o[6] = f2bs(b.z); o[7] = f2bs(b.w);
        ((short8*)xb)[i] = o;
    } else if (bid < 3936) {                // W: 3 mats x 288 blocks
        int seg = bid - 3072;
        int mat = seg / 288, blk = seg % 288;
        const float* src = (mat == 0) ? wq : (mat == 1) ? wk : wv;
        int i = blk * 256 + tid;
        float4 a = ((const float4*)src)[2 * i];
        float4 b = ((const float4*)src)[2 * i + 1];
        short8 o;
        o[0] = f2bs(a.x); o[1] = f2bs(a.y); o[2] = f2bs(a.z); o[3] = f2bs(a.w);
        o[4] = f2bs(b.x); o[5] = f2bs(b.y); o[6] = f2bs(b.z); o[7] = f2bs(b.w);
        ((short8*)(Wb + (size_t)mat * HID * HID))[i] = o;
    } else if (bid < 3996) {                // bilit: [s,h,p,q] -> bf16 [s,h,q,p]
        int sh = bid - 3936;
        const float* src = bili + (size_t)sh * 4096;
        short* dst = bltb + (size_t)sh * 4096;
        for (int t = tid; t < 4096; t += 256) Tl[t >> 6][t & 63] = f2bs(src[t]);
        __syncthreads();
        for (int t = tid; t < 4096; t += 256) dst[t] = Tl[t & 63][t >> 6];
    } else {                                // maskT: 1024 blocks, one 64x64 (i,j) tile each
        int t = bid - 3996;
        int b = t >> 6;
        int tile = t & 63;
        int ib0 = (tile >> 3) * 64, jb0 = (tile & 7) * 64;
        unsigned* Ml = (unsigned*)Tl;       // 64 rows x 20 dwords (5120 B < 9216)
        const size_t BLL = (size_t)BATCH * SEQ * SEQ;
        // thread owns 4x4 sub-tile: rows 4rg..4rg+3, cols 4cg..4cg+3
        const int rg = tid >> 4, cg = tid & 15;
        const float* sm = smask + ((size_t)b * SEQ + (ib0 + 4 * rg)) * SEQ + jb0 + 4 * cg;
        unsigned dw[4] = {0u, 0u, 0u, 0u};  // dw[cc]: byte rr = mask bits for row 4rg+rr
#pragma unroll
        for (int s = 0; s < NS; ++s) {
            const float* ss = sm + (size_t)s * BLL;
#pragma unroll
            for (int rr = 0; rr < 4; ++rr) {
                float4 v = *(const float4*)(ss + (size_t)rr * SEQ);
                const unsigned bit = (1u << s);
                dw[0] |= (v.x != 0.f) ? (bit << (8 * rr)) : 0u;
                dw[1] |= (v.y != 0.f) ? (bit << (8 * rr)) : 0u;
                dw[2] |= (v.z != 0.f) ? (bit << (8 * rr)) : 0u;
                dw[3] |= (v.w != 0.f) ? (bit << (8 * rr)) : 0u;
            }
        }
#pragma unroll
        for (int cc = 0; cc < 4; ++cc)
            Ml[(4 * cg + cc) * 20 + rg] = dw[cc];   // row j, dword rg (80 B rows, uint4-aligned)
        __syncthreads();
        const int j = tid >> 2, ig = tid & 3;
        uint4 val = *(const uint4*)&Ml[j * 20 + 4 * ig];
        *(uint4*)&mT[((size_t)b * SEQ + jb0 + j) * SEQ + ib0 + 16 * ig] = val;
    }
}

// ---------- QKV projection: 128x128 tile, DOUBLE-BUFFERED global_load_lds staging ----------
// q pre-scaled by 0.125*LOG2E; k raw; v -> transposed [B,H,D,L].
// One barrier per K-iter: prefetch tile k+1 issued after the barrier that guarantees tile k
// arrived, so the DMA overlaps tile k's 16 MFMAs (attn R10 pattern). LDS: 2x16 KB buffers,
// pool reused as 4x8 KB per-wave epilogue transpose scratch.
__global__ __launch_bounds__(256) void proj_mfma(
    const short* __restrict__ xb, const short* __restrict__ Wb,
    const float* __restrict__ bq, const float* __restrict__ bk, const float* __restrict__ bv,
    short* __restrict__ qo, short* __restrict__ ko, short* __restrict__ vto)
{
    __shared__ short SMEM[16384];    // 32 KB pool: buf p at p*8192 (As 4096 + Bs 4096 shorts)

    const int tid = threadIdx.x, lane = tid & 63, w = tid >> 6;
    const int q4 = lane >> 4, c15 = lane & 15;
    const int m0 = blockIdx.x * 128, n0 = blockIdx.y * 128;
    const int wrow = (w & 1) * 64, wcol = (w >> 1) * 64;

    const int srow = lane >> 2;
    const int scol = (lane & 3) * 8;
    const short* gA = xb + (size_t)(m0 + w * 32 + srow) * HID + scol;
    const short* gB = Wb + (size_t)(n0 + w * 32 + srow) * HID + scol;

    floatx4 acc[4][4];
#pragma unroll
    for (int i = 0; i < 4; ++i)
#pragma unroll
        for (int j = 0; j < 4; ++j) acc[i][j] = (floatx4){0.f, 0.f, 0.f, 0.f};

    // prefetch k-tile 0 into buffer 0
    {
        short* lA = SMEM + w * 1024;
        short* lB = SMEM + 4096 + w * 1024;
        GLOAD16(gA,            lA);
        GLOAD16(gA + 16 * HID, lA + 512);
        GLOAD16(gB,            lB);
        GLOAD16(gB + 16 * HID, lB + 512);
    }

    for (int it = 0; it < HID / 32; ++it) {
        __syncthreads();   // tile it arrived; buffer (it+1)&1 free (its readers finished pre-barrier)
        if (it + 1 < HID / 32) {
            const int k0 = (it + 1) * 32;
            short* base = SMEM + ((it + 1) & 1) * 8192;
            short* lA = base + w * 1024;
            short* lB = base + 4096 + w * 1024;
            GLOAD16(gA + k0,            lA);
            GLOAD16(gA + k0 + 16 * HID, lA + 512);
            GLOAD16(gB + k0,            lB);
            GLOAD16(gB + k0 + 16 * HID, lB + 512);
        }
        const short* As = SMEM + (it & 1) * 8192;
        const short* Bs = As + 4096;

        short8 af[4], bf[4];
#pragma unroll
        for (int ri = 0; ri < 4; ++ri)
            af[ri] = *(const short8*)&As[(wrow + ri * 16 + c15) * 32 + q4 * 8];
#pragma unroll
        for (int ci = 0; ci < 4; ++ci)
            bf[ci] = *(const short8*)&Bs[(wcol + ci * 16 + c15) * 32 + q4 * 8];
#pragma unroll
        for (int ri = 0; ri < 4; ++ri)
#pragma unroll
            for (int ci = 0; ci < 4; ++ci)
                acc[ri][ci] = MFMA16(af[ri], bf[ci], acc[ri][ci]);
    }

    __syncthreads();   // all frag reads done before reusing pool as epilogue scratch

    short* Sw = SMEM + w * 4096;   // per-wave disjoint 8 KB scratch

    const int matq = n0 / HID;
    const float* bias = (matq == 0) ? bq : (matq == 1) ? bk : bv;
    const int nmBase = (n0 - matq * HID) + wcol;
    const int h = nmBase >> 6;
    const int mg0 = m0 + wrow;
    const int bb = mg0 >> 9, l0 = mg0 & 511;

    if (matq < 2) {
        const float qsc = (matq == 0) ? (0.125f * LOG2E) : 1.0f;
#pragma unroll
        for (int ci = 0; ci < 4; ++ci) {
            const int col = ci * 16 + c15;
            const float bv2 = bias[nmBase + col];
#pragma unroll
            for (int ri = 0; ri < 4; ++ri)
#pragma unroll
                for (int r = 0; r < 4; ++r) {
                    const int row = ri * 16 + q4 * 4 + r;
                    const int phys = (row << 6) + ((((col >> 3) ^ (row & 7)) << 3) | (col & 7));
                    Sw[phys] = f2bs((acc[ri][ci][r] + bv2) * qsc);
                }
        }
        short* dst = (matq == 0) ? qo : ko;
#pragma unroll
        for (int it2 = 0; it2 < 8; ++it2) {
            const int row = it2 * 8 + (lane >> 3);
            const int g = lane & 7;
            short8 val = *(const short8*)&Sw[(row << 6) + ((g ^ (row & 7)) << 3)];
            *(short8*)&dst[(((size_t)bb * NH + h) * SEQ + (l0 + row)) * HD + g * 8] = val;
        }
    } else {
#pragma unroll
        for (int ci = 0; ci < 4; ++ci) {
            const int d = ci * 16 + c15;
            const float bv2 = bias[nmBase + d];
#pragma unroll
            for (int ri = 0; ri < 4; ++ri) {
                bs4 v4;
#pragma unroll
                for (int r = 0; r < 4; ++r) v4[r] = f2bs(acc[ri][ci][r] + bv2);
                const int lbase = ri * 16 + q4 * 4;
                const int phys = (d << 6) + ((((lbase >> 3) ^ (d & 7)) << 3) | (lbase & 7));
                *(bs4*)&Sw[phys] = v4;
            }
        }
#pragma unroll
        for (int it2 = 0; it2 < 8; ++it2) {
            const int d = it2 * 8 + (lane >> 3);
            const int g = lane & 7;
            short8 val = *(const short8*)&Sw[(d << 6) + ((g ^ (d & 7)) << 3)];
            *(short8*)&vto[(((size_t)bb * NH + h) * HD + d) * SEQ + l0 + g * 8] = val;
        }
    }
}

// ---------- fused biaffine attention: dbuf global_load_lds K/V + transposed-mask dwords ----------
// block = (64 q-rows of one (b,h)); 256 threads / 4 waves; wave w owns rows w*16..+15.
// NOTE: no min-waves clause — R9's (256,4) capped VGPRs at 64 -> ~400 MB spill traffic.
__global__ __launch_bounds__(256) void attn_mfma(
    const short* __restrict__ q, const short* __restrict__ k, const short* __restrict__ vt,
    const unsigned char* __restrict__ mT, const float* __restrict__ amask,
    const short* __restrict__ bilit, const float* __restrict__ abs_bias,
    float* __restrict__ out)
{
    __shared__ short KsB[2][4096];   // 64 rows x 64 shorts, chunk-swizzled
    __shared__ short VsB[2][4096];
    __shared__ short Pw[4][16 * 40]; // per-wave P/Qp transpose scratch (32 cols + pad)
    __shared__ float Am[SEQ];        // amask[b]*LOG2E
    __shared__ float abt[32];        // LOG2E*0.125*sum(bits*ab) - 23 (fixed exp2 shift)

    const int idx = blockIdx.x;
    const int bh = idx % 192, it = idx / 192;
    const int b = bh / NH, h = bh % NH;
    const int i0 = it * 64;
    const int tid = threadIdx.x, lane = tid & 63, w = tid >> 6;
    const int q4 = lane >> 4, c15 = lane & 15, x7 = c15 & 7;

    const short* qg = q + (size_t)bh * SEQ * HD;
    const short* kg = k + (size_t)bh * SEQ * HD;
    const short* vg = vt + (size_t)bh * HD * SEQ;

    // staging geometry: slot s = w*128 + i*64 + lane ; r = s>>3 ; phys chunk = s&7 ; global chunk = (s&7)^(r&7)
    const int s0 = w * 128 + lane;
    const int r0 = s0 >> 3, cg0 = (s0 & 7) ^ (r0 & 7);
    const int s1 = s0 + 64;
    const int r1 = s1 >> 3, cg1 = (s1 & 7) ^ (r1 & 7);

    // prefetch tile 0 (overlaps prologue compute)
    GLOAD16(kg + (size_t)r0 * HD + cg0 * 8, &KsB[0][w * 1024]);
    GLOAD16(kg + (size_t)r1 * HD + cg1 * 8, &KsB[0][w * 1024 + 512]);
    GLOAD16(vg + (size_t)r0 * SEQ + cg0 * 8, &VsB[0][w * 1024]);
    GLOAD16(vg + (size_t)r1 * SEQ + cg1 * 8, &VsB[0][w * 1024 + 512]);

    if (tid < 32) {
        float a = 0.f;
#pragma unroll
        for (int s = 0; s < NS; ++s)
            if (tid & (1u << s)) a += abs_bias[s * NH + h];
        abt[tid] = a * (0.125f * LOG2E) - 23.0f;
    }
    for (int c = tid; c < SEQ; c += 256) Am[c] = amask[b * SEQ + c] * LOG2E;

    // Q A-fragments straight from global
    short8 aQ0 = *(const short8*)&qg[(size_t)(i0 + w * 16 + c15) * HD + q4 * 8];
    short8 aQ1 = *(const short8*)&qg[(size_t)(i0 + w * 16 + c15) * HD + 32 + q4 * 8];

    // Qp prologue: 2 passes of 32 cols through the 40-stride Pw (wave-private, no barrier)
    short* pw = &Pw[w][0];
    short8 aP[NS][2];
#pragma unroll
    for (int s = 0; s < NS; ++s) {
        const short* bt = bilit + ((size_t)s * NH + h) * 4096;
#pragma unroll
        for (int half = 0; half < 2; ++half) {
#pragma unroll
            for (int n2 = 0; n2 < 2; ++n2) {
                const int ns = half * 2 + n2;
                short8 bf0 = *(const short8*)&bt[(ns * 16 + c15) * 64 + q4 * 8];
                short8 bf1 = *(const short8*)&bt[(ns * 16 + c15) * 64 + 32 + q4 * 8];
                floatx4 acc = {0.f, 0.f, 0.f, 0.f};
                acc = MFMA16(aQ0, bf0, acc);
                acc = MFMA16(aQ1, bf1, acc);
#pragma unroll
                for (int r = 0; r < 4; ++r)
                    pw[(q4 * 4 + r) * 40 + n2 * 16 + c15] = f2bs(acc[r]);
            }
            aP[s][half] = *(const short8*)&pw[c15 * 40 + q4 * 8];
        }
    }

    float l_part[4] = {0.f, 0.f, 0.f, 0.f};
    floatx4 O[4];
#pragma unroll
    for (int d = 0; d < 4; ++d) O[d] = (floatx4){0.f, 0.f, 0.f, 0.f};

    const int ibase = i0 + w * 16 + q4 * 4;
    const unsigned char* mTb = mT + (size_t)b * SEQ * SEQ;   // [j][i], i contiguous

    // mask dwords for jt=0 (4 i-rows per dword)
    unsigned mv[4];
#pragma unroll
    for (int js = 0; js < 4; ++js)
        mv[js] = *(const unsigned*)&mTb[(size_t)(js * 16 + c15) * SEQ + ibase];

    for (int jt = 0; jt < 8; ++jt) {
        const int j0 = jt * 64;
        __syncthreads();   // tile jt arrived (vmcnt drain) + prior readers of the other buffer done

        // prefetch tile jt+1 (DMA overlaps this tile's compute) + mask dwords jt+1
        unsigned mvn[4] = {0u, 0u, 0u, 0u};
        if (jt < 7) {
            const int jn = j0 + 64;
            short* kb_ = &KsB[(jt + 1) & 1][w * 1024];
            short* vb_ = &VsB[(jt + 1) & 1][w * 1024];
            GLOAD16(kg + (size_t)(jn + r0) * HD + cg0 * 8, kb_);
            GLOAD16(kg + (size_t)(jn + r1) * HD + cg1 * 8, kb_ + 512);
            GLOAD16(vg + (size_t)r0 * SEQ + jn + cg0 * 8, vb_);
            GLOAD16(vg + (size_t)r1 * SEQ + jn + cg1 * 8, vb_ + 512);
#pragma unroll
            for (int js = 0; js < 4; ++js)
                mvn[js] = *(const unsigned*)&mTb[(size_t)(jn + js * 16 + c15) * SEQ + ibase];
        }

        const short* Kc = KsB[jt & 1];
        const short* Vc = VsB[jt & 1];

#pragma unroll
        for (int js = 0; js < 4; ++js) {
            const int row = js * 16 + c15;
            short8 kf0 = *(const short8*)&Kc[row * 64 + ((q4 ^ x7) << 3)];
            short8 kf1 = *(const short8*)&Kc[row * 64 + (((4 + q4) ^ x7) << 3)];

            floatx4 a0 = {0.f, 0.f, 0.f, 0.f};
            a0 = MFMA16(aQ0, kf0, a0);
            a0 = MFMA16(aQ1, kf1, a0);
            floatx4 as_[NS];
#pragma unroll
            for (int s = 0; s < NS; ++s) {
                floatx4 tacc = {0.f, 0.f, 0.f, 0.f};
                tacc = MFMA16(aP[s][0], kf0, tacc);
                tacc = MFMA16(aP[s][1], kf1, tacc);
                as_[s] = tacc;
            }
            const float amv = Am[j0 + js * 16 + c15];
#pragma unroll
            for (int r = 0; r < 4; ++r) {
                const unsigned mbyte = (mv[js] >> (8 * r)) & 0xffu;
                float sc = a0[r] + amv + abt[mbyte & 31u];
#pragma unroll
                for (int s = 0; s < NS; ++s)
                    sc = fmaf((float)((mbyte >> s) & 1u), as_[s][r], sc);
                float p = __builtin_amdgcn_exp2f(sc);
                l_part[r] += p;
                pw[(q4 * 4 + r) * 40 + (js & 1) * 16 + c15] = f2bs(p);
            }
            if (js & 1) {
                short8 pA = *(const short8*)&pw[c15 * 40 + q4 * 8];
                const int kk = js >> 1;
#pragma unroll
                for (int d = 0; d < 4; ++d) {
                    const int vrow = d * 16 + c15;
                    short8 vb = *(const short8*)&Vc[vrow * 64 + (((kk * 4 + q4) ^ x7) << 3)];
                    O[d] = MFMA16(pA, vb, O[d]);
                }
            }
        }
#pragma unroll
        for (int js = 0; js < 4; ++js) mv[js] = mvn[js];
    }

    // epilogue: reduce l across the 16 j-lanes, normalize, store
#pragma unroll
    for (int r = 0; r < 4; ++r) {
        float l = l_part[r];
        l += __shfl_xor(l, 1);
        l += __shfl_xor(l, 2);
        l += __shfl_xor(l, 4);
        l += __shfl_xor(l, 8);
        float inv = 1.f / l;
        float* orow = out + ((size_t)b * SEQ + ibase + r) * HID + h * HD;
#pragma unroll
        for (int d = 0; d < 4; ++d)
            orow[d * 16 + c15] = O[d][r] * inv;
    }
}

extern "C" void kernel_launch(void* const* d_in, const int* in_sizes, int n_in,
                              void* d_out, int out_size, void* d_ws, size_t ws_size,
                              hipStream_t stream) {
    const float* hidden   = (const float*)d_in[0];
    const float* amask    = (const float*)d_in[1];
    const float* smask    = (const float*)d_in[2];
    const float* Wq       = (const float*)d_in[3];
    const float* bq       = (const float*)d_in[4];
    const float* Wk       = (const float*)d_in[5];
    const float* bk       = (const float*)d_in[6];
    const float* Wv       = (const float*)d_in[7];
    const float* bv       = (const float*)d_in[8];
    const float* bili     = (const float*)d_in[9];
    const float* abs_bias = (const float*)d_in[10];
    float* out = (float*)d_out;

    char* ws = (char*)d_ws;
    const size_t QKV = (size_t)BATCH * NH * SEQ * HD * 2;
    short* qb   = (short*)(ws);
    short* kb   = (short*)(ws + QKV);
    short* vtb  = (short*)(ws + 2 * QKV);
    short* xb   = (short*)(ws + 3 * QKV);
    short* Wb   = (short*)(ws + 4 * QKV);
    short* bltb = (short*)(ws + 4 * QKV + (size_t)3 * HID * HID * 2);
    unsigned char* mT = (unsigned char*)(ws + 4 * QKV + (size_t)3 * HID * HID * 2
                                         + (size_t)NS * NH * HD * HD * 2);

    prep_kernel<<<5020, 256, 0, stream>>>(hidden, Wq, Wk, Wv, bili, smask,
                                          xb, Wb, bltb, mT);

    proj_mfma<<<dim3(BATCH * SEQ / 128, 3 * HID / 128), 256, 0, stream>>>(
        xb, Wb, bq, bk, bv, qb, kb, vtb);

    attn_mfma<<<(SEQ / 64) * NH * BATCH, 256, 0, stream>>>(
        qb, kb, vtb, mT, amask, bltb, abs_bias, out);
}